// Round 1
// baseline (81.837 us; speedup 1.0000x reference)
//
#include <hip/hip_runtime.h>

// B=4, L=1024, H=512, NH=8, D=64
typedef __attribute__((ext_vector_type(8))) short bf16x8;
typedef __attribute__((ext_vector_type(4))) float f32x4;

__device__ __forceinline__ unsigned short f2bf(float f) {
    unsigned int u = __builtin_bit_cast(unsigned int, f);
    u += 0x7fffu + ((u >> 16) & 1u);   // RNE
    return (unsigned short)(u >> 16);
}

// ---------------- projection GEMM: C[m,n] = X[m,:]·W[n,:] + b[n] -------------
// z=0: query->Qb [b][h][l][d], z=1: key->Kb [b][h][l][d], z=2: value->Vt [b][h][d][l]
__global__ __launch_bounds__(256) void proj_kernel(
    const float* __restrict__ query, const float* __restrict__ key_, const float* __restrict__ value,
    const float* __restrict__ wq_w, const float* __restrict__ wq_b,
    const float* __restrict__ wk_w, const float* __restrict__ wk_b,
    const float* __restrict__ wv_w, const float* __restrict__ wv_b,
    unsigned short* __restrict__ Qb, unsigned short* __restrict__ Kb, unsigned short* __restrict__ Vt)
{
    const int z = blockIdx.y;
    const float* X    = (z == 0) ? query : (z == 1) ? key_ : value;
    const float* W    = (z == 0) ? wq_w  : (z == 1) ? wk_w : wv_w;
    const float* bias = (z == 0) ? wq_b  : (z == 1) ? wk_b : wv_b;

    const int t = threadIdx.x;
    const int l = t & 63;
    const int w = t >> 6;
    const int wm = w >> 1, wn = w & 1;       // 2x2 wave grid, 64x64 per wave
    const int bx = blockIdx.x & 3;           // n tile (512/128)
    const int by = blockIdx.x >> 2;          // m tile (4096/128)
    const int m0 = by * 128, n0 = bx * 128;

    __shared__ __align__(16) unsigned short As[128 * 32];
    __shared__ __align__(16) unsigned short Bs[128 * 32];

    f32x4 acc[4][4];
#pragma unroll
    for (int i = 0; i < 4; i++)
#pragma unroll
        for (int j = 0; j < 4; j++) acc[i][j] = (f32x4){0.f, 0.f, 0.f, 0.f};

    for (int k0 = 0; k0 < 512; k0 += 32) {
        __syncthreads();
#pragma unroll
        for (int i = 0; i < 4; i++) {
            int idx = t + 256 * i;
            int row = idx >> 3, c = idx & 7;           // 128 rows x 8 float4-chunks
            float4 a = *(const float4*)(X + (m0 + row) * 512 + k0 + c * 4);
            __align__(8) unsigned short va[4] = {f2bf(a.x), f2bf(a.y), f2bf(a.z), f2bf(a.w)};
            *(uint2*)(As + row * 32 + (((c >> 1) ^ (row & 3)) * 8) + (c & 1) * 4) = *(uint2*)va;
            float4 bq = *(const float4*)(W + (n0 + row) * 512 + k0 + c * 4);
            __align__(8) unsigned short vb[4] = {f2bf(bq.x), f2bf(bq.y), f2bf(bq.z), f2bf(bq.w)};
            *(uint2*)(Bs + row * 32 + (((c >> 1) ^ (row & 3)) * 8) + (c & 1) * 4) = *(uint2*)vb;
        }
        __syncthreads();

        bf16x8 af[4], bfv[4];
#pragma unroll
        for (int mf = 0; mf < 4; mf++) {
            int row = wm * 64 + mf * 16 + (l & 15);
            af[mf] = *(const bf16x8*)(As + row * 32 + (((l >> 4) ^ (row & 3)) * 8));
        }
#pragma unroll
        for (int nf = 0; nf < 4; nf++) {
            int row = wn * 64 + nf * 16 + (l & 15);
            bfv[nf] = *(const bf16x8*)(Bs + row * 32 + (((l >> 4) ^ (row & 3)) * 8));
        }
#pragma unroll
        for (int mf = 0; mf < 4; mf++)
#pragma unroll
            for (int nf = 0; nf < 4; nf++)
                acc[mf][nf] = __builtin_amdgcn_mfma_f32_16x16x32_bf16(af[mf], bfv[nf], acc[mf][nf], 0, 0, 0);
    }

    if (z < 2) {
        unsigned short* dst = (z == 0) ? Qb : Kb;
#pragma unroll
        for (int nf = 0; nf < 4; nf++) {
            int n = n0 + wn * 64 + nf * 16 + (l & 15);
            float bv = bias[n];
            int h = n >> 6, d = n & 63;
#pragma unroll
            for (int mf = 0; mf < 4; mf++) {
                int mbase = m0 + wm * 64 + mf * 16 + 4 * (l >> 4);
                int bb = mbase >> 10;
#pragma unroll
                for (int r = 0; r < 4; r++) {
                    int lq = (mbase + r) & 1023;
                    dst[((size_t)(bb * 8 + h) * 1024 + lq) * 64 + d] = f2bf(acc[mf][nf][r] + bv);
                }
            }
        }
    } else {
#pragma unroll
        for (int nf = 0; nf < 4; nf++) {
            int n = n0 + wn * 64 + nf * 16 + (l & 15);
            float bv = bias[n];
            int h = n >> 6, d = n & 63;
#pragma unroll
            for (int mf = 0; mf < 4; mf++) {
                int mbase = m0 + wm * 64 + mf * 16 + 4 * (l >> 4);
                int bb = mbase >> 10;
                int lq0 = mbase & 1023;                 // 4 consecutive l positions
                ushort4 pk;
                pk.x = f2bf(acc[mf][nf][0] + bv);
                pk.y = f2bf(acc[mf][nf][1] + bv);
                pk.z = f2bf(acc[mf][nf][2] + bv);
                pk.w = f2bf(acc[mf][nf][3] + bv);
                *(ushort4*)(Vt + ((size_t)(bb * 8 + h) * 64 + d) * 1024 + lq0) = pk;
            }
        }
    }
}

// ---------------- fused attention: per (b, h, 64-row q tile) -----------------
__global__ __launch_bounds__(256) void attn_kernel(
    const unsigned short* __restrict__ Qb, const unsigned short* __restrict__ Kb,
    const unsigned short* __restrict__ Vt, const float* __restrict__ rel_pos,
    const int* __restrict__ seq_len, const int* __restrict__ lex_num,
    unsigned short* __restrict__ AO)
{
    const int t = threadIdx.x;
    const int l = t & 63;
    const int w = t >> 6;                    // wave 0..3, owns 16 q rows
    const int qt = blockIdx.x, h = blockIdx.y, b = blockIdx.z;
    const int q0 = qt * 64;
    const int bh = b * 8 + h;
    const int len = seq_len[b] + lex_num[b];
    const int nkt = (len + 63) >> 6;         // only tiles with >=1 valid key

    __shared__ __align__(16) unsigned short Qs[64 * 64];
    __shared__ __align__(16) unsigned short Ks[64 * 64];
    __shared__ __align__(16) unsigned short Vs[64 * 64];   // V^T tile: [d][k]
    __shared__ __align__(16) unsigned short Ps[4 * 16 * 64];

    const unsigned short* Qg = Qb + ((size_t)bh * 1024 + q0) * 64;
    const unsigned short* Kg = Kb + (size_t)bh * 1024 * 64;
    const unsigned short* Vg = Vt + (size_t)bh * 64 * 1024;

    // stage Q once (XOR-swizzled 16B chunks)
#pragma unroll
    for (int i = 0; i < 2; i++) {
        int idx = t + 256 * i;
        int row = idx >> 3, c = idx & 7;
        uint4 v = *(const uint4*)(Qg + row * 64 + c * 8);
        *(uint4*)(Qs + row * 64 + ((c ^ (row & 7)) * 8)) = v;
    }
    __syncthreads();

    bf16x8 qf[2];
    {
        int row = w * 16 + (l & 15);
#pragma unroll
        for (int s = 0; s < 2; s++) {
            int ch = 4 * s + (l >> 4);
            qf[s] = *(const bf16x8*)(Qs + row * 64 + ((ch ^ (row & 7)) * 8));
        }
    }

    f32x4 oacc[4];
#pragma unroll
    for (int dn = 0; dn < 4; dn++) oacc[dn] = (f32x4){0.f, 0.f, 0.f, 0.f};
    float m_run[4] = {-3.0e38f, -3.0e38f, -3.0e38f, -3.0e38f};
    float l_run[4] = {0.f, 0.f, 0.f, 0.f};

    const float* relg = rel_pos + ((size_t)bh * 1024 + q0 + w * 16) * 1024;
    unsigned short* Pw = Ps + w * 1024;

    for (int kt = 0; kt < nkt; kt++) {
        const int k0 = kt * 64;
        __syncthreads();                      // prev PV done before restage
#pragma unroll
        for (int i = 0; i < 2; i++) {
            int idx = t + 256 * i;
            int row = idx >> 3, c = idx & 7;
            uint4 kv = *(const uint4*)(Kg + (size_t)(k0 + row) * 64 + c * 8);
            *(uint4*)(Ks + row * 64 + ((c ^ (row & 7)) * 8)) = kv;
            uint4 vv = *(const uint4*)(Vg + (size_t)row * 1024 + k0 + c * 8);
            *(uint4*)(Vs + row * 64 + ((c ^ (row & 7)) * 8)) = vv;
        }
        __syncthreads();

        // issue rel_pos loads early (independent of the MFMAs)
        float rel[4][4];
#pragma unroll
        for (int kn = 0; kn < 4; kn++)
#pragma unroll
            for (int r = 0; r < 4; r++)
                rel[kn][r] = relg[(size_t)(4 * (l >> 4) + r) * 1024 + k0 + kn * 16 + (l & 15)];

        f32x4 sa[4];
#pragma unroll
        for (int kn = 0; kn < 4; kn++) sa[kn] = (f32x4){0.f, 0.f, 0.f, 0.f};
#pragma unroll
        for (int s = 0; s < 2; s++)
#pragma unroll
            for (int kn = 0; kn < 4; kn++) {
                int krow = kn * 16 + (l & 15);
                int ch = 4 * s + (l >> 4);
                bf16x8 kf = *(const bf16x8*)(Ks + krow * 64 + ((ch ^ (krow & 7)) * 8));
                sa[kn] = __builtin_amdgcn_mfma_f32_16x16x32_bf16(qf[s], kf, sa[kn], 0, 0, 0);
            }

        float p[4][4];
#pragma unroll
        for (int r = 0; r < 4; r++) {
            float sv[4];
#pragma unroll
            for (int kn = 0; kn < 4; kn++) {
                int kg = k0 + kn * 16 + (l & 15);
                float x = sa[kn][r] * 0.125f + rel[kn][r];
                sv[kn] = (kg < len) ? x : -1e15f;
            }
            float mx = fmaxf(fmaxf(sv[0], sv[1]), fmaxf(sv[2], sv[3]));
#pragma unroll
            for (int o = 1; o < 16; o <<= 1) mx = fmaxf(mx, __shfl_xor(mx, o, 64));
            float mn = fmaxf(m_run[r], mx);
            float scale = __expf(m_run[r] - mn);
            m_run[r] = mn;
            float rs = 0.f;
#pragma unroll
            for (int kn = 0; kn < 4; kn++) { p[kn][r] = __expf(sv[kn] - mn); rs += p[kn][r]; }
#pragma unroll
            for (int o = 1; o < 16; o <<= 1) rs += __shfl_xor(rs, o, 64);
            l_run[r] = l_run[r] * scale + rs;
#pragma unroll
            for (int dn = 0; dn < 4; dn++) oacc[dn][r] *= scale;
        }

        // P (D-layout) -> LDS in A-frag layout, bf16
#pragma unroll
        for (int kn = 0; kn < 4; kn++)
#pragma unroll
            for (int r = 0; r < 4; r++) {
                int qrow = 4 * (l >> 4) + r;
                int k = kn * 16 + (l & 15);
                Pw[qrow * 64 + (((k >> 3) ^ (qrow & 7)) * 8) + (k & 7)] = f2bf(p[kn][r]);
            }
        __syncthreads();

        // PV: out[q][d] += P[q,k]·V[k,d]
#pragma unroll
        for (int s = 0; s < 2; s++) {
            int arow = (l & 15);
            bf16x8 pf = *(const bf16x8*)(Pw + arow * 64 + (((4 * s + (l >> 4)) ^ (arow & 7)) * 8));
#pragma unroll
            for (int dn = 0; dn < 4; dn++) {
                int drow = dn * 16 + (l & 15);
                bf16x8 vf = *(const bf16x8*)(Vs + drow * 64 + (((4 * s + (l >> 4)) ^ (drow & 7)) * 8));
                oacc[dn] = __builtin_amdgcn_mfma_f32_16x16x32_bf16(pf, vf, oacc[dn], 0, 0, 0);
            }
        }
    }

    // epilogue: normalize, store bf16 to AO[b*1024+q][h*64+d]
    unsigned short* AOg = AO + ((size_t)(b * 1024 + q0 + w * 16)) * 512 + h * 64;
#pragma unroll
    for (int r = 0; r < 4; r++) {
        float inv = 1.0f / l_run[r];
        int qrow = 4 * (l >> 4) + r;
#pragma unroll
        for (int dn = 0; dn < 4; dn++)
            AOg[(size_t)qrow * 512 + dn * 16 + (l & 15)] = f2bf(oacc[dn][r] * inv);
    }
}

// ---------------- FF GEMM: out[m,n] = AO[m,:]·ff_w[n,:] + ff_b[n] (f32 out) ---
__global__ __launch_bounds__(256) void ff_kernel(
    const unsigned short* __restrict__ AO, const float* __restrict__ ff_w,
    const float* __restrict__ ff_b, float* __restrict__ out)
{
    const int t = threadIdx.x;
    const int l = t & 63;
    const int w = t >> 6;
    const int wm = w >> 1, wn = w & 1;
    const int bx = blockIdx.x & 3;
    const int by = blockIdx.x >> 2;
    const int m0 = by * 128, n0 = bx * 128;

    __shared__ __align__(16) unsigned short As[128 * 32];
    __shared__ __align__(16) unsigned short Bs[128 * 32];

    f32x4 acc[4][4];
#pragma unroll
    for (int i = 0; i < 4; i++)
#pragma unroll
        for (int j = 0; j < 4; j++) acc[i][j] = (f32x4){0.f, 0.f, 0.f, 0.f};

    for (int k0 = 0; k0 < 512; k0 += 32) {
        __syncthreads();
#pragma unroll
        for (int i = 0; i < 2; i++) {
            int idx = t + 256 * i;
            int row = idx >> 2, c = idx & 3;
            uint4 v = *(const uint4*)(AO + (size_t)(m0 + row) * 512 + k0 + c * 8);
            *(uint4*)(As + row * 32 + ((c ^ (row & 3)) * 8)) = v;
        }
#pragma unroll
        for (int i = 0; i < 4; i++) {
            int idx = t + 256 * i;
            int row = idx >> 3, c = idx & 7;
            float4 bq = *(const float4*)(ff_w + (n0 + row) * 512 + k0 + c * 4);
            __align__(8) unsigned short vb[4] = {f2bf(bq.x), f2bf(bq.y), f2bf(bq.z), f2bf(bq.w)};
            *(uint2*)(Bs + row * 32 + (((c >> 1) ^ (row & 3)) * 8) + (c & 1) * 4) = *(uint2*)vb;
        }
        __syncthreads();

        bf16x8 af[4], bfv[4];
#pragma unroll
        for (int mf = 0; mf < 4; mf++) {
            int row = wm * 64 + mf * 16 + (l & 15);
            af[mf] = *(const bf16x8*)(As + row * 32 + (((l >> 4) ^ (row & 3)) * 8));
        }
#pragma unroll
        for (int nf = 0; nf < 4; nf++) {
            int row = wn * 64 + nf * 16 + (l & 15);
            bfv[nf] = *(const bf16x8*)(Bs + row * 32 + (((l >> 4) ^ (row & 3)) * 8));
        }
#pragma unroll
        for (int mf = 0; mf < 4; mf++)
#pragma unroll
            for (int nf = 0; nf < 4; nf++)
                acc[mf][nf] = __builtin_amdgcn_mfma_f32_16x16x32_bf16(af[mf], bfv[nf], acc[mf][nf], 0, 0, 0);
    }

#pragma unroll
    for (int nf = 0; nf < 4; nf++) {
        int n = n0 + wn * 64 + nf * 16 + (l & 15);
        float bv = ff_b[n];
#pragma unroll
        for (int mf = 0; mf < 4; mf++) {
            int mbase = m0 + wm * 64 + mf * 16 + 4 * (l >> 4);
#pragma unroll
            for (int r = 0; r < 4; r++)
                out[(size_t)(mbase + r) * 512 + n] = acc[mf][nf][r] + bv;
        }
    }
}

extern "C" void kernel_launch(void* const* d_in, const int* in_sizes, int n_in,
                              void* d_out, int out_size, void* d_ws, size_t ws_size,
                              hipStream_t stream) {
    const float* key   = (const float*)d_in[0];
    const float* query = (const float*)d_in[1];
    const float* value = (const float*)d_in[2];
    const float* rel   = (const float*)d_in[3];
    const float* wk_w  = (const float*)d_in[4];
    const float* wk_b  = (const float*)d_in[5];
    const float* wq_w  = (const float*)d_in[6];
    const float* wq_b  = (const float*)d_in[7];
    const float* wv_w  = (const float*)d_in[8];
    const float* wv_b  = (const float*)d_in[9];
    const float* ff_w  = (const float*)d_in[10];
    const float* ff_b  = (const float*)d_in[11];
    const int* seq_len = (const int*)d_in[12];
    const int* lex_num = (const int*)d_in[13];
    float* out = (float*)d_out;

    unsigned short* Qb = (unsigned short*)d_ws;     // [4][8][1024][64] bf16, 4 MB
    unsigned short* Kb = Qb + 2097152;              // 4 MB
    unsigned short* Vt = Kb + 2097152;              // [4][8][64][1024] bf16, 4 MB
    unsigned short* AO = Vt + 2097152;              // [4096][512] bf16, 4 MB

    proj_kernel<<<dim3(128, 3), 256, 0, stream>>>(query, key, value,
                                                  wq_w, wq_b, wk_w, wk_b, wv_w, wv_b,
                                                  Qb, Kb, Vt);
    attn_kernel<<<dim3(16, 8, 4), 256, 0, stream>>>(Qb, Kb, Vt, rel, seq_len, lex_num, AO);
    ff_kernel<<<dim3(128), 256, 0, stream>>>(AO, ff_w, ff_b, out);
}

// Round 3
// 70.798 us; speedup vs baseline: 1.1559x; 1.1559x over previous
//
#include <hip/hip_runtime.h>
#include <hip/hip_bf16.h>

// B=4, L=1024, H=512, NH=8, D=64
typedef __attribute__((ext_vector_type(8))) short bf16x8;
typedef __attribute__((ext_vector_type(4))) float f32x4;

__device__ __forceinline__ unsigned short f2bf(float f) {
    return __builtin_bit_cast(unsigned short, __float2bfloat16(f));
}

typedef const __attribute__((address_space(1))) void gvoid;
typedef __attribute__((address_space(3))) void lvoid;
#define GLDS(g, s) __builtin_amdgcn_global_load_lds((gvoid*)(g), (lvoid*)(s), 16, 0, 0)

__device__ __forceinline__ void block_barrier() {
    asm volatile("" ::: "memory");
    __builtin_amdgcn_s_barrier();
    asm volatile("" ::: "memory");
}

// ---------------- projection GEMM: C[m,n] = X[m,:]·W[n,:] + b[n] -------------
// z=0: query->Qb [b][h][l][d], z=1: key->Kb [b][h][l][d], z=2: value->Vt [b][h][d][l]
__global__ __launch_bounds__(256) void proj_kernel(
    const float* __restrict__ query, const float* __restrict__ key_, const float* __restrict__ value,
    const float* __restrict__ wq_w, const float* __restrict__ wq_b,
    const float* __restrict__ wk_w, const float* __restrict__ wk_b,
    const float* __restrict__ wv_w, const float* __restrict__ wv_b,
    unsigned short* __restrict__ Qb, unsigned short* __restrict__ Kb, unsigned short* __restrict__ Vt)
{
    const int z = blockIdx.y;
    const float* X    = (z == 0) ? query : (z == 1) ? key_ : value;
    const float* W    = (z == 0) ? wq_w  : (z == 1) ? wk_w : wv_w;
    const float* bias = (z == 0) ? wq_b  : (z == 1) ? wk_b : wv_b;

    const int t = threadIdx.x;
    const int l = t & 63;
    const int w = t >> 6;
    const int wm = w >> 1, wn = w & 1;       // 2x2 wave grid, 64x64 per wave
    const int bx = blockIdx.x & 3;           // n tile (512/128)
    const int by = blockIdx.x >> 2;          // m tile (4096/128)
    const int m0 = by * 128, n0 = bx * 128;

    __shared__ __align__(16) unsigned short As[128 * 32];
    __shared__ __align__(16) unsigned short Bs[128 * 32];

    f32x4 acc[4][4];
#pragma unroll
    for (int i = 0; i < 4; i++)
#pragma unroll
        for (int j = 0; j < 4; j++) acc[i][j] = (f32x4){0.f, 0.f, 0.f, 0.f};

    float4 ra[4], rb[4];
    auto LOAD = [&](int k0) {
#pragma unroll
        for (int i = 0; i < 4; i++) {
            int idx = t + 256 * i;
            int row = idx >> 3, c = idx & 7;
            ra[i] = *(const float4*)(X + (size_t)(m0 + row) * 512 + k0 + c * 4);
            rb[i] = *(const float4*)(W + (size_t)(n0 + row) * 512 + k0 + c * 4);
        }
    };
    LOAD(0);

    for (int k0 = 0; k0 < 512; k0 += 32) {
        if (k0) block_barrier();             // prev frag reads consumed by MFMAs
#pragma unroll
        for (int i = 0; i < 4; i++) {
            int idx = t + 256 * i;
            int row = idx >> 3, c = idx & 7;
            __align__(8) unsigned short va[4] = {f2bf(ra[i].x), f2bf(ra[i].y), f2bf(ra[i].z), f2bf(ra[i].w)};
            *(uint2*)(As + row * 32 + (((c >> 1) ^ (row & 3)) * 8) + (c & 1) * 4) = *(uint2*)va;
            __align__(8) unsigned short vb[4] = {f2bf(rb[i].x), f2bf(rb[i].y), f2bf(rb[i].z), f2bf(rb[i].w)};
            *(uint2*)(Bs + row * 32 + (((c >> 1) ^ (row & 3)) * 8) + (c & 1) * 4) = *(uint2*)vb;
        }
        asm volatile("s_waitcnt lgkmcnt(0)" ::: "memory");
        block_barrier();
        if (k0 + 32 < 512) LOAD(k0 + 32);    // prefetch overlaps MFMA below

        bf16x8 af[4], bfv[4];
#pragma unroll
        for (int mf = 0; mf < 4; mf++) {
            int row = wm * 64 + mf * 16 + (l & 15);
            af[mf] = *(const bf16x8*)(As + row * 32 + (((l >> 4) ^ (row & 3)) * 8));
        }
#pragma unroll
        for (int nf = 0; nf < 4; nf++) {
            int row = wn * 64 + nf * 16 + (l & 15);
            bfv[nf] = *(const bf16x8*)(Bs + row * 32 + (((l >> 4) ^ (row & 3)) * 8));
        }
#pragma unroll
        for (int mf = 0; mf < 4; mf++)
#pragma unroll
            for (int nf = 0; nf < 4; nf++)
                acc[mf][nf] = __builtin_amdgcn_mfma_f32_16x16x32_bf16(af[mf], bfv[nf], acc[mf][nf], 0, 0, 0);
    }

    if (z < 2) {
        unsigned short* dst = (z == 0) ? Qb : Kb;
#pragma unroll
        for (int nf = 0; nf < 4; nf++) {
            int n = n0 + wn * 64 + nf * 16 + (l & 15);
            float bv = bias[n];
            int h = n >> 6, d = n & 63;
#pragma unroll
            for (int mf = 0; mf < 4; mf++) {
                int mbase = m0 + wm * 64 + mf * 16 + 4 * (l >> 4);
                int bb = mbase >> 10;
#pragma unroll
                for (int r = 0; r < 4; r++) {
                    int lq = (mbase + r) & 1023;
                    dst[((size_t)(bb * 8 + h) * 1024 + lq) * 64 + d] = f2bf(acc[mf][nf][r] + bv);
                }
            }
        }
    } else {
#pragma unroll
        for (int nf = 0; nf < 4; nf++) {
            int n = n0 + wn * 64 + nf * 16 + (l & 15);
            float bv = bias[n];
            int h = n >> 6, d = n & 63;
#pragma unroll
            for (int mf = 0; mf < 4; mf++) {
                int mbase = m0 + wm * 64 + mf * 16 + 4 * (l >> 4);
                int bb = mbase >> 10;
                int lq0 = mbase & 1023;                 // 4 consecutive l positions
                ushort4 pk;
                pk.x = f2bf(acc[mf][nf][0] + bv);
                pk.y = f2bf(acc[mf][nf][1] + bv);
                pk.z = f2bf(acc[mf][nf][2] + bv);
                pk.w = f2bf(acc[mf][nf][3] + bv);
                *(ushort4*)(Vt + ((size_t)(bb * 8 + h) * 64 + d) * 1024 + lq0) = pk;
            }
        }
    }
}

// ---------------- fused attention: per (b, h, 64-row q tile) -----------------
// Async double-buffered staging of K/V/rel via global_load_lds; counted vmcnt;
// raw barriers (no vmcnt(0) drain mid-loop).
__global__ __launch_bounds__(256) void attn_kernel(
    const unsigned short* __restrict__ Qb, const unsigned short* __restrict__ Kb,
    const unsigned short* __restrict__ Vt, const float* __restrict__ rel_pos,
    const int* __restrict__ seq_len, const int* __restrict__ lex_num,
    unsigned short* __restrict__ AO)
{
    const int t = threadIdx.x;
    const int l = t & 63;
    const int w = t >> 6;                    // wave 0..3, owns 16 q rows
    const int qt = blockIdx.x, h = blockIdx.y, b = blockIdx.z;
    const int q0 = qt * 64;
    const int bh = b * 8 + h;
    const int len = seq_len[b] + lex_num[b];
    const int nkt = (len + 63) >> 6;         // only tiles with >=1 valid key

    __shared__ __align__(16) unsigned short Qs[64 * 64];
    __shared__ __align__(16) unsigned short Ks[2][64 * 64];
    __shared__ __align__(16) unsigned short Vs[2][64 * 64];   // V^T tile: [d][k]
    __shared__ __align__(16) float Rs[2][64 * 64];            // rel tile: [q][k]
    __shared__ __align__(16) unsigned short Ps[4 * 16 * 64];

    const unsigned short* Qg = Qb + ((size_t)bh * 1024 + q0) * 64;
    const unsigned short* Kg = Kb + (size_t)bh * 1024 * 64;
    const unsigned short* Vg = Vt + (size_t)bh * 64 * 1024;
    const float* Rg = rel_pos + ((size_t)bh * 1024 + q0) * 1024;

    // per-lane async-staging geometry (LDS dest is linear lane*16B; swizzle the SOURCE)
    const int rl8 = l >> 3, c8 = l & 7;      // K/V/Q: 8 rows x 8 chunks (16B) per instr
    const int kvc = (c8 ^ rl8) * 8;          // swizzled source col (shorts); row&7 == rl8
    const int rl16 = l >> 4, c16 = l & 15;   // rel: 4 rows x 16 chunks (16B) per instr

    auto STAGE = [&](int kt, int nb) {
        const int k0 = kt * 64;
#pragma unroll
        for (int j = 0; j < 2; j++) {
            int row = w * 16 + j * 8 + rl8;
            GLDS(Kg + (size_t)(k0 + row) * 64 + kvc, &Ks[nb][(w * 16 + j * 8) * 64]);
            GLDS(Vg + (size_t)row * 1024 + k0 + kvc, &Vs[nb][(w * 16 + j * 8) * 64]);
        }
#pragma unroll
        for (int j = 0; j < 4; j++) {
            int row = w * 16 + j * 4 + rl16;
            int cc = c16 ^ ((j * 4 + rl16) & 7);
            GLDS(Rg + (size_t)row * 1024 + k0 + cc * 4, &Rs[nb][(w * 16 + j * 4) * 64]);
        }
    };

    STAGE(0, 0);                             // 8 loads
#pragma unroll
    for (int j = 0; j < 2; j++) {            // Q: 2 loads
        int row = w * 16 + j * 8 + rl8;
        GLDS(Qg + (size_t)row * 64 + kvc, &Qs[(w * 16 + j * 8) * 64]);
    }
    asm volatile("s_waitcnt vmcnt(0)" ::: "memory");
    block_barrier();

    bf16x8 qf[2];
#pragma unroll
    for (int s = 0; s < 2; s++) {
        int row = w * 16 + (l & 15);
        int ch = 4 * s + (l >> 4);
        qf[s] = *(const bf16x8*)(Qs + row * 64 + ((ch ^ (row & 7)) * 8));
    }

    f32x4 oacc[4];
#pragma unroll
    for (int dn = 0; dn < 4; dn++) oacc[dn] = (f32x4){0.f, 0.f, 0.f, 0.f};
    float m_run[4] = {-3.0e38f, -3.0e38f, -3.0e38f, -3.0e38f};
    float l_run[4] = {0.f, 0.f, 0.f, 0.f};

    unsigned short* Pw = Ps + w * 1024;

    for (int kt = 0; kt < nkt; kt++) {
        const int cur = kt & 1;
        const int k0 = kt * 64;
        if (kt + 1 < nkt) {
            STAGE(kt + 1, cur ^ 1);          // prefetch next tile (8 loads in flight)
            asm volatile("s_waitcnt vmcnt(8)" ::: "memory");
        } else {
            asm volatile("s_waitcnt vmcnt(0)" ::: "memory");
        }
        block_barrier();                     // tile kt visible to all waves

        const unsigned short* Ksc = Ks[cur];
        const unsigned short* Vsc = Vs[cur];
        const float* Rsc = Rs[cur];

        // rel from LDS — wave w's q-rows live at tile rows w*16 + qrow
        float rel[4][4];
#pragma unroll
        for (int kn = 0; kn < 4; kn++) {
            int ccb = kn * 4 + ((l >> 2) & 3);
#pragma unroll
            for (int r = 0; r < 4; r++) {
                int qrow = 4 * (l >> 4) + r;
                rel[kn][r] = Rsc[(w * 16 + qrow) * 64 + ((ccb ^ (qrow & 7)) * 4) + (l & 3)];
            }
        }

        f32x4 sa[4];
#pragma unroll
        for (int kn = 0; kn < 4; kn++) sa[kn] = (f32x4){0.f, 0.f, 0.f, 0.f};
#pragma unroll
        for (int s = 0; s < 2; s++)
#pragma unroll
            for (int kn = 0; kn < 4; kn++) {
                int krow = kn * 16 + (l & 15);
                int ch = 4 * s + (l >> 4);
                bf16x8 kf = *(const bf16x8*)(Ksc + krow * 64 + ((ch ^ (krow & 7)) * 8));
                sa[kn] = __builtin_amdgcn_mfma_f32_16x16x32_bf16(qf[s], kf, sa[kn], 0, 0, 0);
            }

        float p[4][4];
#pragma unroll
        for (int r = 0; r < 4; r++) {
            float sv[4];
#pragma unroll
            for (int kn = 0; kn < 4; kn++) {
                int kg = k0 + kn * 16 + (l & 15);
                float x = sa[kn][r] * 0.125f + rel[kn][r];
                sv[kn] = (kg < len) ? x : -1e15f;
            }
            float mx = fmaxf(fmaxf(sv[0], sv[1]), fmaxf(sv[2], sv[3]));
#pragma unroll
            for (int o = 1; o < 16; o <<= 1) mx = fmaxf(mx, __shfl_xor(mx, o, 64));
            float mn = fmaxf(m_run[r], mx);
            float scale = __expf(m_run[r] - mn);
            m_run[r] = mn;
            float rs = 0.f;
#pragma unroll
            for (int kn = 0; kn < 4; kn++) { p[kn][r] = __expf(sv[kn] - mn); rs += p[kn][r]; }
#pragma unroll
            for (int o = 1; o < 16; o <<= 1) rs += __shfl_xor(rs, o, 64);
            l_run[r] = l_run[r] * scale + rs;
#pragma unroll
            for (int dn = 0; dn < 4; dn++) oacc[dn][r] *= scale;
        }

        // P (D-layout) -> LDS in A-frag layout, bf16 (own wave's region; no barrier)
#pragma unroll
        for (int kn = 0; kn < 4; kn++)
#pragma unroll
            for (int r = 0; r < 4; r++) {
                int qrow = 4 * (l >> 4) + r;
                int k = kn * 16 + (l & 15);
                Pw[qrow * 64 + (((k >> 3) ^ (qrow & 7)) * 8) + (k & 7)] = f2bf(p[kn][r]);
            }

        // PV: out[q][d] += P[q,k]·V[k,d]
#pragma unroll
        for (int s = 0; s < 2; s++) {
            int arow = (l & 15);
            bf16x8 pf = *(const bf16x8*)(Pw + arow * 64 + (((4 * s + (l >> 4)) ^ (arow & 7)) * 8));
#pragma unroll
            for (int dn = 0; dn < 4; dn++) {
                int drow = dn * 16 + (l & 15);
                bf16x8 vf = *(const bf16x8*)(Vsc + drow * 64 + (((4 * s + (l >> 4)) ^ (drow & 7)) * 8));
                oacc[dn] = __builtin_amdgcn_mfma_f32_16x16x32_bf16(pf, vf, oacc[dn], 0, 0, 0);
            }
        }
        block_barrier();                     // all reads of buf[cur] done before overwrite
    }

    // epilogue: normalize, store bf16 to AO[b*1024+q][h*64+d]
    unsigned short* AOg = AO + ((size_t)(b * 1024 + q0 + w * 16)) * 512 + h * 64;
#pragma unroll
    for (int r = 0; r < 4; r++) {
        float inv = 1.0f / l_run[r];
        int qrow = 4 * (l >> 4) + r;
#pragma unroll
        for (int dn = 0; dn < 4; dn++)
            AOg[(size_t)qrow * 512 + dn * 16 + (l & 15)] = f2bf(oacc[dn][r] * inv);
    }
}

// ---------------- FF GEMM: out[m,n] = AO[m,:]·ff_w[n,:] + ff_b[n] (f32 out) ---
// 64x128 tiles -> 256 blocks (1/CU), reg-prefetch double buffer
__global__ __launch_bounds__(256) void ff_kernel(
    const unsigned short* __restrict__ AO, const float* __restrict__ ff_w,
    const float* __restrict__ ff_b, float* __restrict__ out)
{
    const int t = threadIdx.x;
    const int l = t & 63;
    const int w = t >> 6;
    const int wm = w >> 1, wn = w & 1;       // 2x2 waves of 32x64
    const int by = blockIdx.x >> 2;          // m tile (4096/64)
    const int bx = blockIdx.x & 3;           // n tile (512/128)
    const int m0 = by * 64, n0 = bx * 128;

    __shared__ __align__(16) unsigned short As[64 * 32];
    __shared__ __align__(16) unsigned short Bs[128 * 32];

    f32x4 acc[2][4];
#pragma unroll
    for (int i = 0; i < 2; i++)
#pragma unroll
        for (int j = 0; j < 4; j++) acc[i][j] = (f32x4){0.f, 0.f, 0.f, 0.f};

    uint4 ua;
    float4 rbf[4];
    const int arow = t >> 2, ac = t & 3;
    auto LOAD = [&](int k0) {
        ua = *(const uint4*)(AO + (size_t)(m0 + arow) * 512 + k0 + ac * 8);
#pragma unroll
        for (int i = 0; i < 4; i++) {
            int idx = t + 256 * i;
            int row = idx >> 3, c = idx & 7;
            rbf[i] = *(const float4*)(ff_w + (size_t)(n0 + row) * 512 + k0 + c * 4);
        }
    };
    LOAD(0);

    for (int k0 = 0; k0 < 512; k0 += 32) {
        if (k0) block_barrier();
        *(uint4*)(As + arow * 32 + ((ac ^ (arow & 3)) * 8)) = ua;
#pragma unroll
        for (int i = 0; i < 4; i++) {
            int idx = t + 256 * i;
            int row = idx >> 3, c = idx & 7;
            __align__(8) unsigned short vb[4] = {f2bf(rbf[i].x), f2bf(rbf[i].y), f2bf(rbf[i].z), f2bf(rbf[i].w)};
            *(uint2*)(Bs + row * 32 + (((c >> 1) ^ (row & 3)) * 8) + (c & 1) * 4) = *(uint2*)vb;
        }
        asm volatile("s_waitcnt lgkmcnt(0)" ::: "memory");
        block_barrier();
        if (k0 + 32 < 512) LOAD(k0 + 32);

        bf16x8 af[2], bfv[4];
#pragma unroll
        for (int mf = 0; mf < 2; mf++) {
            int row = wm * 32 + mf * 16 + (l & 15);
            af[mf] = *(const bf16x8*)(As + row * 32 + (((l >> 4) ^ (row & 3)) * 8));
        }
#pragma unroll
        for (int nf = 0; nf < 4; nf++) {
            int row = wn * 64 + nf * 16 + (l & 15);
            bfv[nf] = *(const bf16x8*)(Bs + row * 32 + (((l >> 4) ^ (row & 3)) * 8));
        }
#pragma unroll
        for (int mf = 0; mf < 2; mf++)
#pragma unroll
            for (int nf = 0; nf < 4; nf++)
                acc[mf][nf] = __builtin_amdgcn_mfma_f32_16x16x32_bf16(af[mf], bfv[nf], acc[mf][nf], 0, 0, 0);
    }

#pragma unroll
    for (int nf = 0; nf < 4; nf++) {
        int n = n0 + wn * 64 + nf * 16 + (l & 15);
        float bv = ff_b[n];
#pragma unroll
        for (int mf = 0; mf < 2; mf++) {
            int mbase = m0 + wm * 32 + mf * 16 + 4 * (l >> 4);
#pragma unroll
            for (int r = 0; r < 4; r++)
                out[(size_t)(mbase + r) * 512 + n] = acc[mf][nf][r] + bv;
        }
    }
}

extern "C" void kernel_launch(void* const* d_in, const int* in_sizes, int n_in,
                              void* d_out, int out_size, void* d_ws, size_t ws_size,
                              hipStream_t stream) {
    const float* key   = (const float*)d_in[0];
    const float* query = (const float*)d_in[1];
    const float* value = (const float*)d_in[2];
    const float* rel   = (const float*)d_in[3];
    const float* wk_w  = (const float*)d_in[4];
    const float* wk_b  = (const float*)d_in[5];
    const float* wq_w  = (const float*)d_in[6];
    const float* wq_b  = (const float*)d_in[7];
    const float* wv_w  = (const float*)d_in[8];
    const float* wv_b  = (const float*)d_in[9];
    const float* ff_w  = (const float*)d_in[10];
    const float* ff_b  = (const float*)d_in[11];
    const int* seq_len = (const int*)d_in[12];
    const int* lex_num = (const int*)d_in[13];
    float* out = (float*)d_out;

    unsigned short* Qb = (unsigned short*)d_ws;     // [4][8][1024][64] bf16, 4 MB
    unsigned short* Kb = Qb + 2097152;              // 4 MB
    unsigned short* Vt = Kb + 2097152;              // [4][8][64][1024] bf16, 4 MB
    unsigned short* AO = Vt + 2097152;              // [4096][512] bf16, 4 MB

    proj_kernel<<<dim3(128, 3), 256, 0, stream>>>(query, key, value,
                                                  wq_w, wq_b, wk_w, wk_b, wv_w, wv_b,
                                                  Qb, Kb, Vt);
    attn_kernel<<<dim3(16, 8, 4), 256, 0, stream>>>(Qb, Kb, Vt, rel, seq_len, lex_num, AO);
    ff_kernel<<<dim3(256), 256, 0, stream>>>(AO, ff_w, ff_b, out);
}

// Round 5
// 69.681 us; speedup vs baseline: 1.1744x; 1.0160x over previous
//
#include <hip/hip_runtime.h>
#include <hip/hip_bf16.h>

// B=4, L=1024, H=512, NH=8, D=64
typedef __attribute__((ext_vector_type(8))) short bf16x8;
typedef __attribute__((ext_vector_type(4))) float f32x4;

__device__ __forceinline__ unsigned short f2bf(float f) {
    return __builtin_bit_cast(unsigned short, __float2bfloat16(f));
}

typedef const __attribute__((address_space(1))) void gvoid;
typedef __attribute__((address_space(3))) void lvoid;
#define GLDS(g, s) __builtin_amdgcn_global_load_lds((gvoid*)(g), (lvoid*)(s), 16, 0, 0)

__device__ __forceinline__ void block_barrier() {
    asm volatile("" ::: "memory");
    __builtin_amdgcn_s_barrier();
    asm volatile("" ::: "memory");
}

// ---------------- projection GEMM: C[m,n] = X[m,:]·W[n,:] + b[n] -------------
// z=0: query->Qb [b][h][l][d], z=1: key->Kb [b][h][l][d], z=2: value->Vt [b][h][d][l]
// 1-D grid of 384, XCD-swizzled: 48 consecutive wids per XCD -> n-blocks sharing
// an A panel land on the same XCD L2.
__global__ __launch_bounds__(256) void proj_kernel(
    const float* __restrict__ query, const float* __restrict__ key_, const float* __restrict__ value,
    const float* __restrict__ wq_w, const float* __restrict__ wq_b,
    const float* __restrict__ wk_w, const float* __restrict__ wk_b,
    const float* __restrict__ wv_w, const float* __restrict__ wv_b,
    unsigned short* __restrict__ Qb, unsigned short* __restrict__ Kb, unsigned short* __restrict__ Vt)
{
    const int wid = (blockIdx.x & 7) * 48 + (blockIdx.x >> 3);   // bijective, 48 blocks/XCD
    const int z = wid >> 7;
    const int rr = wid & 127;
    const int by = rr >> 2, bx = rr & 3;

    const float* X    = (z == 0) ? query : (z == 1) ? key_ : value;
    const float* W    = (z == 0) ? wq_w  : (z == 1) ? wk_w : wv_w;
    const float* bias = (z == 0) ? wq_b  : (z == 1) ? wk_b : wv_b;

    const int t = threadIdx.x;
    const int l = t & 63;
    const int w = t >> 6;
    const int wm = w >> 1, wn = w & 1;       // 2x2 wave grid, 64x64 per wave
    const int m0 = by * 128, n0 = bx * 128;

    __shared__ __align__(16) unsigned short As[128 * 32];
    __shared__ __align__(16) unsigned short Bs[128 * 32];

    f32x4 acc[4][4];
#pragma unroll
    for (int i = 0; i < 4; i++)
#pragma unroll
        for (int j = 0; j < 4; j++) acc[i][j] = (f32x4){0.f, 0.f, 0.f, 0.f};

    float4 ra[4], rb[4];
    auto LOAD = [&](int k0) {
#pragma unroll
        for (int i = 0; i < 4; i++) {
            int idx = t + 256 * i;
            int row = idx >> 3, c = idx & 7;
            ra[i] = *(const float4*)(X + (size_t)(m0 + row) * 512 + k0 + c * 4);
            rb[i] = *(const float4*)(W + (size_t)(n0 + row) * 512 + k0 + c * 4);
        }
    };
    LOAD(0);

    for (int k0 = 0; k0 < 512; k0 += 32) {
        if (k0) block_barrier();             // prev frag reads consumed by MFMAs
#pragma unroll
        for (int i = 0; i < 4; i++) {
            int idx = t + 256 * i;
            int row = idx >> 3, c = idx & 7;
            __align__(8) unsigned short va[4] = {f2bf(ra[i].x), f2bf(ra[i].y), f2bf(ra[i].z), f2bf(ra[i].w)};
            *(uint2*)(As + row * 32 + (((c >> 1) ^ (row & 3)) * 8) + (c & 1) * 4) = *(uint2*)va;
            __align__(8) unsigned short vb[4] = {f2bf(rb[i].x), f2bf(rb[i].y), f2bf(rb[i].z), f2bf(rb[i].w)};
            *(uint2*)(Bs + row * 32 + (((c >> 1) ^ (row & 3)) * 8) + (c & 1) * 4) = *(uint2*)vb;
        }
        asm volatile("s_waitcnt lgkmcnt(0)" ::: "memory");
        block_barrier();
        if (k0 + 32 < 512) LOAD(k0 + 32);    // prefetch overlaps MFMA below

        bf16x8 af[4], bfv[4];
#pragma unroll
        for (int mf = 0; mf < 4; mf++) {
            int row = wm * 64 + mf * 16 + (l & 15);
            af[mf] = *(const bf16x8*)(As + row * 32 + (((l >> 4) ^ (row & 3)) * 8));
        }
#pragma unroll
        for (int nf = 0; nf < 4; nf++) {
            int row = wn * 64 + nf * 16 + (l & 15);
            bfv[nf] = *(const bf16x8*)(Bs + row * 32 + (((l >> 4) ^ (row & 3)) * 8));
        }
#pragma unroll
        for (int mf = 0; mf < 4; mf++)
#pragma unroll
            for (int nf = 0; nf < 4; nf++)
                acc[mf][nf] = __builtin_amdgcn_mfma_f32_16x16x32_bf16(af[mf], bfv[nf], acc[mf][nf], 0, 0, 0);
    }

    if (z < 2) {
        unsigned short* dst = (z == 0) ? Qb : Kb;
#pragma unroll
        for (int nf = 0; nf < 4; nf++) {
            int n = n0 + wn * 64 + nf * 16 + (l & 15);
            float bv = bias[n];
            int h = n >> 6, d = n & 63;
#pragma unroll
            for (int mf = 0; mf < 4; mf++) {
                int mbase = m0 + wm * 64 + mf * 16 + 4 * (l >> 4);
                int bb = mbase >> 10;
#pragma unroll
                for (int r = 0; r < 4; r++) {
                    int lq = (mbase + r) & 1023;
                    dst[((size_t)(bb * 8 + h) * 1024 + lq) * 64 + d] = f2bf(acc[mf][nf][r] + bv);
                }
            }
        }
    } else {
#pragma unroll
        for (int nf = 0; nf < 4; nf++) {
            int n = n0 + wn * 64 + nf * 16 + (l & 15);
            float bv = bias[n];
            int h = n >> 6, d = n & 63;
#pragma unroll
            for (int mf = 0; mf < 4; mf++) {
                int mbase = m0 + wm * 64 + mf * 16 + 4 * (l >> 4);
                int bb = mbase >> 10;
                int lq0 = mbase & 1023;                 // 4 consecutive l positions
                ushort4 pk;
                pk.x = f2bf(acc[mf][nf][0] + bv);
                pk.y = f2bf(acc[mf][nf][1] + bv);
                pk.z = f2bf(acc[mf][nf][2] + bv);
                pk.w = f2bf(acc[mf][nf][3] + bv);
                *(ushort4*)(Vt + ((size_t)(bb * 8 + h) * 64 + d) * 1024 + lq0) = pk;
            }
        }
    }
}

// ---------------- fused attention: per (b, h, 64-row q tile) -----------------
// Async double-buffered staging of K/V/rel via global_load_lds; counted vmcnt;
// raw barriers. XCD swizzle: each XCD owns 4 whole (b,h) groups, distinct b.
__global__ __launch_bounds__(256) void attn_kernel(
    const unsigned short* __restrict__ Qb, const unsigned short* __restrict__ Kb,
    const unsigned short* __restrict__ Vt, const float* __restrict__ rel_pos,
    const int* __restrict__ seq_len, const int* __restrict__ lex_num,
    unsigned short* __restrict__ AO)
{
    const int t = threadIdx.x;
    const int l = t & 63;
    const int w = t >> 6;                    // wave 0..3, owns 16 q rows
    // 512 blocks; XCD x8 gets 64 consecutive wids = 4 (b,h) groups, b = 0..3 (balanced)
    const int wid = (blockIdx.x & 7) * 64 + (blockIdx.x >> 3);
    const int x8 = wid >> 6;
    const int g  = (wid >> 4) & 3;
    const int qt = wid & 15;
    const int b  = g;
    const int h  = (x8 + 2 * g) & 7;
    const int q0 = qt * 64;
    const int bh = b * 8 + h;
    const int len = seq_len[b] + lex_num[b];
    const int nkt = (len + 63) >> 6;         // only tiles with >=1 valid key

    __shared__ __align__(16) unsigned short Qs[64 * 64];
    __shared__ __align__(16) unsigned short Ks[2][64 * 64];
    __shared__ __align__(16) unsigned short Vs[2][64 * 64];   // V^T tile: [d][k]
    __shared__ __align__(16) float Rs[2][64 * 64];            // rel tile: [q][k]
    __shared__ __align__(16) unsigned short Ps[4 * 16 * 64];

    const unsigned short* Qg = Qb + ((size_t)bh * 1024 + q0) * 64;
    const unsigned short* Kg = Kb + (size_t)bh * 1024 * 64;
    const unsigned short* Vg = Vt + (size_t)bh * 64 * 1024;
    const float* Rg = rel_pos + ((size_t)bh * 1024 + q0) * 1024;

    // per-lane async-staging geometry (LDS dest is linear lane*16B; swizzle the SOURCE)
    const int rl8 = l >> 3, c8 = l & 7;      // K/V/Q: 8 rows x 8 chunks (16B) per instr
    const int kvc = (c8 ^ rl8) * 8;          // swizzled source col (shorts); row&7 == rl8
    const int rl16 = l >> 4, c16 = l & 15;   // rel: 4 rows x 16 chunks (16B) per instr

    auto STAGE = [&](int kt, int nb) {       // 8 GLDS per thread-wave slice
        const int k0 = kt * 64;
#pragma unroll
        for (int j = 0; j < 2; j++) {
            int row = w * 16 + j * 8 + rl8;
            GLDS(Kg + (size_t)(k0 + row) * 64 + kvc, &Ks[nb][(w * 16 + j * 8) * 64]);
            GLDS(Vg + (size_t)row * 1024 + k0 + kvc, &Vs[nb][(w * 16 + j * 8) * 64]);
        }
#pragma unroll
        for (int j = 0; j < 4; j++) {
            int row = w * 16 + j * 4 + rl16;
            int cc = c16 ^ ((j * 4 + rl16) & 7);
            GLDS(Rg + (size_t)row * 1024 + k0 + cc * 4, &Rs[nb][(w * 16 + j * 4) * 64]);
        }
    };

    STAGE(0, 0);                             // 8 loads
#pragma unroll
    for (int j = 0; j < 2; j++) {            // Q: 2 loads
        int row = w * 16 + j * 8 + rl8;
        GLDS(Qg + (size_t)row * 64 + kvc, &Qs[(w * 16 + j * 8) * 64]);
    }
    asm volatile("s_waitcnt vmcnt(0)" ::: "memory");
    block_barrier();

    bf16x8 qf[2];
#pragma unroll
    for (int s = 0; s < 2; s++) {
        int row = w * 16 + (l & 15);
        int ch = 4 * s + (l >> 4);
        qf[s] = *(const bf16x8*)(Qs + row * 64 + ((ch ^ (row & 7)) * 8));
    }

    f32x4 oacc[4];
#pragma unroll
    for (int dn = 0; dn < 4; dn++) oacc[dn] = (f32x4){0.f, 0.f, 0.f, 0.f};
    float m_run[4] = {-3.0e38f, -3.0e38f, -3.0e38f, -3.0e38f};
    float l_run[4] = {0.f, 0.f, 0.f, 0.f};

    unsigned short* Pw = Ps + w * 1024;

    for (int kt = 0; kt < nkt; kt++) {
        const int cur = kt & 1;
        const int k0 = kt * 64;
        if (kt + 1 < nkt) {
            STAGE(kt + 1, cur ^ 1);          // prefetch next tile (8 loads in flight)
            asm volatile("s_waitcnt vmcnt(8)" ::: "memory");
        } else {
            asm volatile("s_waitcnt vmcnt(0)" ::: "memory");
        }
        block_barrier();                     // tile kt visible to all waves

        const unsigned short* Ksc = Ks[cur];
        const unsigned short* Vsc = Vs[cur];
        const float* Rsc = Rs[cur];

        // rel from LDS — wave w's q-rows live at tile rows w*16 + qrow
        float rel[4][4];
#pragma unroll
        for (int kn = 0; kn < 4; kn++) {
            int ccb = kn * 4 + ((l >> 2) & 3);
#pragma unroll
            for (int r = 0; r < 4; r++) {
                int qrow = 4 * (l >> 4) + r;
                rel[kn][r] = Rsc[(w * 16 + qrow) * 64 + ((ccb ^ (qrow & 7)) * 4) + (l & 3)];
            }
        }

        f32x4 sa[4];
#pragma unroll
        for (int kn = 0; kn < 4; kn++) sa[kn] = (f32x4){0.f, 0.f, 0.f, 0.f};
        __builtin_amdgcn_s_setprio(1);
#pragma unroll
        for (int s = 0; s < 2; s++)
#pragma unroll
            for (int kn = 0; kn < 4; kn++) {
                int krow = kn * 16 + (l & 15);
                int ch = 4 * s + (l >> 4);
                bf16x8 kf = *(const bf16x8*)(Ksc + krow * 64 + ((ch ^ (krow & 7)) * 8));
                sa[kn] = __builtin_amdgcn_mfma_f32_16x16x32_bf16(qf[s], kf, sa[kn], 0, 0, 0);
            }
        __builtin_amdgcn_s_setprio(0);

        float p[4][4];
#pragma unroll
        for (int r = 0; r < 4; r++) {
            float sv[4];
#pragma unroll
            for (int kn = 0; kn < 4; kn++) {
                int kg = k0 + kn * 16 + (l & 15);
                float x = sa[kn][r] * 0.125f + rel[kn][r];
                sv[kn] = (kg < len) ? x : -1e15f;
            }
            float mx = fmaxf(fmaxf(sv[0], sv[1]), fmaxf(sv[2], sv[3]));
#pragma unroll
            for (int o = 1; o < 16; o <<= 1) mx = fmaxf(mx, __shfl_xor(mx, o, 64));
            float mn = fmaxf(m_run[r], mx);
            float scale = __expf(m_run[r] - mn);
            m_run[r] = mn;
            float rs = 0.f;
#pragma unroll
            for (int kn = 0; kn < 4; kn++) { p[kn][r] = __expf(sv[kn] - mn); rs += p[kn][r]; }
#pragma unroll
            for (int o = 1; o < 16; o <<= 1) rs += __shfl_xor(rs, o, 64);
            l_run[r] = l_run[r] * scale + rs;
#pragma unroll
            for (int dn = 0; dn < 4; dn++) oacc[dn][r] *= scale;
        }

        // P (D-layout) -> LDS in A-frag layout, bf16 (own wave's region; no barrier)
#pragma unroll
        for (int kn = 0; kn < 4; kn++)
#pragma unroll
            for (int r = 0; r < 4; r++) {
                int qrow = 4 * (l >> 4) + r;
                int k = kn * 16 + (l & 15);
                Pw[qrow * 64 + (((k >> 3) ^ (qrow & 7)) * 8) + (k & 7)] = f2bf(p[kn][r]);
            }

        // PV: out[q][d] += P[q,k]·V[k,d]
        __builtin_amdgcn_s_setprio(1);
#pragma unroll
        for (int s = 0; s < 2; s++) {
            int arow = (l & 15);
            bf16x8 pf = *(const bf16x8*)(Pw + arow * 64 + (((4 * s + (l >> 4)) ^ (arow & 7)) * 8));
#pragma unroll
            for (int dn = 0; dn < 4; dn++) {
                int drow = dn * 16 + (l & 15);
                bf16x8 vf = *(const bf16x8*)(Vsc + drow * 64 + (((4 * s + (l >> 4)) ^ (drow & 7)) * 8));
                oacc[dn] = __builtin_amdgcn_mfma_f32_16x16x32_bf16(pf, vf, oacc[dn], 0, 0, 0);
            }
        }
        __builtin_amdgcn_s_setprio(0);
        block_barrier();                     // all reads of buf[cur] done before overwrite
    }

    // epilogue: normalize, store bf16 to AO[b*1024+q][h*64+d]
    unsigned short* AOg = AO + ((size_t)(b * 1024 + q0 + w * 16)) * 512 + h * 64;
#pragma unroll
    for (int r = 0; r < 4; r++) {
        float inv = 1.0f / l_run[r];
        int qrow = 4 * (l >> 4) + r;
#pragma unroll
        for (int dn = 0; dn < 4; dn++)
            AOg[(size_t)qrow * 512 + dn * 16 + (l & 15)] = f2bf(oacc[dn][r] * inv);
    }
}

// ---------------- FF GEMM: out[m,n] = AO[m,:]·ff_w[n,:] + ff_b[n] (f32 out) ---
// 64x128 tiles -> 256 blocks (1/CU), reg-prefetch double buffer, XCD swizzle
__global__ __launch_bounds__(256) void ff_kernel(
    const unsigned short* __restrict__ AO, const float* __restrict__ ff_w,
    const float* __restrict__ ff_b, float* __restrict__ out)
{
    const int t = threadIdx.x;
    const int l = t & 63;
    const int w = t >> 6;
    const int wm = w >> 1, wn = w & 1;       // 2x2 waves of 32x64
    const int wid = (blockIdx.x & 7) * 32 + (blockIdx.x >> 3);
    const int by = wid >> 2;                 // m tile (4096/64)
    const int bx = wid & 3;                  // n tile (512/128)
    const int m0 = by * 64, n0 = bx * 128;

    __shared__ __align__(16) unsigned short As[64 * 32];
    __shared__ __align__(16) unsigned short Bs[128 * 32];

    f32x4 acc[2][4];
#pragma unroll
    for (int i = 0; i < 2; i++)
#pragma unroll
        for (int j = 0; j < 4; j++) acc[i][j] = (f32x4){0.f, 0.f, 0.f, 0.f};

    uint4 ua;
    float4 rbf[4];
    const int arow = t >> 2, ac = t & 3;
    auto LOAD = [&](int k0) {
        ua = *(const uint4*)(AO + (size_t)(m0 + arow) * 512 + k0 + ac * 8);
#pragma unroll
        for (int i = 0; i < 4; i++) {
            int idx = t + 256 * i;
            int row = idx >> 3, c = idx & 7;
            rbf[i] = *(const float4*)(ff_w + (size_t)(n0 + row) * 512 + k0 + c * 4);
        }
    };
    LOAD(0);

    for (int k0 = 0; k0 < 512; k0 += 32) {
        if (k0) block_barrier();
        *(uint4*)(As + arow * 32 + ((ac ^ (arow & 3)) * 8)) = ua;
#pragma unroll
        for (int i = 0; i < 4; i++) {
            int idx = t + 256 * i;
            int row = idx >> 3, c = idx & 7;
            __align__(8) unsigned short vb[4] = {f2bf(rbf[i].x), f2bf(rbf[i].y), f2bf(rbf[i].z), f2bf(rbf[i].w)};
            *(uint2*)(Bs + row * 32 + (((c >> 1) ^ (row & 3)) * 8) + (c & 1) * 4) = *(uint2*)vb;
        }
        asm volatile("s_waitcnt lgkmcnt(0)" ::: "memory");
        block_barrier();
        if (k0 + 32 < 512) LOAD(k0 + 32);

        bf16x8 af[2], bfv[4];
#pragma unroll
        for (int mf = 0; mf < 2; mf++) {
            int row = wm * 32 + mf * 16 + (l & 15);
            af[mf] = *(const bf16x8*)(As + row * 32 + (((l >> 4) ^ (row & 3)) * 8));
        }
#pragma unroll
        for (int nf = 0; nf < 4; nf++) {
            int row = wn * 64 + nf * 16 + (l & 15);
            bfv[nf] = *(const bf16x8*)(Bs + row * 32 + (((l >> 4) ^ (row & 3)) * 8));
        }
#pragma unroll
        for (int mf = 0; mf < 2; mf++)
#pragma unroll
            for (int nf = 0; nf < 4; nf++)
                acc[mf][nf] = __builtin_amdgcn_mfma_f32_16x16x32_bf16(af[mf], bfv[nf], acc[mf][nf], 0, 0, 0);
    }

#pragma unroll
    for (int nf = 0; nf < 4; nf++) {
        int n = n0 + wn * 64 + nf * 16 + (l & 15);
        float bv = ff_b[n];
#pragma unroll
        for (int mf = 0; mf < 2; mf++) {
            int mbase = m0 + wm * 32 + mf * 16 + 4 * (l >> 4);
#pragma unroll
            for (int r = 0; r < 4; r++)
                out[(size_t)(mbase + r) * 512 + n] = acc[mf][nf][r] + bv;
        }
    }
}

extern "C" void kernel_launch(void* const* d_in, const int* in_sizes, int n_in,
                              void* d_out, int out_size, void* d_ws, size_t ws_size,
                              hipStream_t stream) {
    const float* key   = (const float*)d_in[0];
    const float* query = (const float*)d_in[1];
    const float* value = (const float*)d_in[2];
    const float* rel   = (const float*)d_in[3];
    const float* wk_w  = (const float*)d_in[4];
    const float* wk_b  = (const float*)d_in[5];
    const float* wq_w  = (const float*)d_in[6];
    const float* wq_b  = (const float*)d_in[7];
    const float* wv_w  = (const float*)d_in[8];
    const float* wv_b  = (const float*)d_in[9];
    const float* ff_w  = (const float*)d_in[10];
    const float* ff_b  = (const float*)d_in[11];
    const int* seq_len = (const int*)d_in[12];
    const int* lex_num = (const int*)d_in[13];
    float* out = (float*)d_out;

    unsigned short* Qb = (unsigned short*)d_ws;     // [4][8][1024][64] bf16, 4 MB
    unsigned short* Kb = Qb + 2097152;              // 4 MB
    unsigned short* Vt = Kb + 2097152;              // [4][8][64][1024] bf16, 4 MB
    unsigned short* AO = Vt + 2097152;              // [4096][512] bf16, 4 MB

    proj_kernel<<<dim3(384), 256, 0, stream>>>(query, key, value,
                                               wq_w, wq_b, wk_w, wk_b, wv_w, wv_b,
                                               Qb, Kb, Vt);
    attn_kernel<<<dim3(512), 256, 0, stream>>>(Qb, Kb, Vt, rel, seq_len, lex_num, AO);
    ff_kernel<<<dim3(256), 256, 0, stream>>>(AO, ff_w, ff_b, out);
}